// Round 7
// baseline (157.482 us; speedup 1.0000x reference)
//
#include <hip/hip_runtime.h>
#include <math.h>

#define B_ 16
#define T_ 12
#define N_ 325
#define C_ 64
#define K_ 8
#define L_ 3900            // N_*T_
#define M_ 249600          // C_*L_
#define LCH_ 61            // ceil(L_/64)
#define LOG2PI_ 1.8378770664093453f

// ---------------- workspace layout (floats) ----------------
#define OFF_LOGGAM 0            // 128
#define OFF_PART   128          // 256 (16 used)
#define OFF_CTR    384          // 17 unsigned: ctrb[16], ctr2
#define OFF_MUS    512          // 8192
#define OFF_ISIG   8704         // 8192
#define OFF_T1     16896        // 8192
#define OFF_SPART  25088        // 7808 = 128*61
#define OFF_GPART  32896        // 7808 = 976*8
#define OFF_P      40704        // 499200 = B*K*L
#define OFF_CONVP  539904       // 998400 = 61*16384
// total = 1538304 floats = 6.15 MB

// K1: per (lc,b): stage raw rep_aug tile, L2-normalize over C in-LDS,
//     conv partials (c=lane) AND gamma partials (l=lane, coalesced Wg).
__global__ __launch_bounds__(256) void k1(const float* __restrict__ rep_aug,
                                          const float* __restrict__ Wg,
                                          const float* __restrict__ Wmu,
                                          const float* __restrict__ Wsg,
                                          float* __restrict__ gpart,
                                          float* __restrict__ convp) {
    int b = blockIdx.x & 15, lc = blockIdx.x >> 4;
    int l0 = lc * 64;
    __shared__ float ldsA[64 * 65];      // [ll][c]
    __shared__ float sc[64];
    __shared__ float ldsW[16 * 64];
    int tid = threadIdx.x, lane = tid & 63, wv = tid >> 6;
    const float4* r4 = (const float4*)rep_aug;
    for (int i4 = tid; i4 < 1024; i4 += 256) {
        int ll = i4 >> 4, c4 = i4 & 15;
        int l = l0 + ll;
        float4 v = make_float4(0.f, 0.f, 0.f, 0.f);
        if (l < L_) {
            int n = l / T_, t = l - n * T_;
            v = r4[(size_t)((b * T_ + t) * N_ + n) * 16 + c4];
        }
        int base = ll * 65 + c4 * 4;
        ldsA[base] = v.x; ldsA[base+1] = v.y; ldsA[base+2] = v.z; ldsA[base+3] = v.w;
    }
    for (int idx = tid; idx < 1024; idx += 256) {
        int r = idx >> 6, ll = idx & 63;
        int l = l0 + ll;
        float w = 0.0f;
        if (l < L_) w = (r < 8) ? Wmu[r * L_ + l] : Wsg[(r - 8) * L_ + l];
        ldsW[r * 64 + ll] = w;
    }
    __syncthreads();
    #pragma unroll 4
    for (int i = 0; i < 16; ++i) {
        int p = wv * 16 + i;
        float x = ldsA[p * 65 + lane];
        float ss = x * x;
        #pragma unroll
        for (int m = 1; m < 64; m <<= 1) ss += __shfl_xor(ss, m);
        if (lane == 0) sc[p] = 1.0f / fmaxf(sqrtf(ss), 1e-12f);
    }
    __syncthreads();

    // ---- gamma partials: lane = l (coalesced Wg), wave wv owns k0,k1 ----
    int k0 = wv * 2, k1 = k0 + 1;
    int lg = l0 + lane;
    int lcl = lg < L_ ? lg : 0;          // invalid lanes have a==0, load harmless
    const float* pg0 = Wg + (size_t)k0 * M_ + lcl;
    const float* pg1 = Wg + (size_t)k1 * M_ + lcl;
    float scv = sc[lane];
    float g0 = 0.f, g1 = 0.f;
    #pragma unroll 8
    for (int c = 0; c < 64; ++c) {
        float a = ldsA[lane * 65 + c] * scv;
        g0 = fmaf(a, pg0[(size_t)c * L_], g0);
        g1 = fmaf(a, pg1[(size_t)c * L_], g1);
    }
    #pragma unroll
    for (int m = 1; m < 64; m <<= 1) { g0 += __shfl_xor(g0, m); g1 += __shfl_xor(g1, m); }
    if (lane == 0) {
        gpart[(size_t)blockIdx.x * 8 + k0] = g0;
        gpart[(size_t)blockIdx.x * 8 + k1] = g1;
    }

    // ---- conv partials: c = lane, kk = wv (LDS-only) ----
    int c = lane, kk = wv;
    const float* w0 = &ldsW[(kk * 4 + 0) * 64];
    const float* w1 = &ldsW[(kk * 4 + 1) * 64];
    const float* w2 = &ldsW[(kk * 4 + 2) * 64];
    const float* w3 = &ldsW[(kk * 4 + 3) * 64];
    float a0 = 0.f, a1 = 0.f, a2 = 0.f, a3 = 0.f;
    #pragma unroll 8
    for (int l = 0; l < 64; ++l) {
        float a = ldsA[l * 65 + c] * sc[l];
        a0 = fmaf(a, w0[l], a0);
        a1 = fmaf(a, w1[l], a1);
        a2 = fmaf(a, w2[l], a2);
        a3 = fmaf(a, w3[l], a3);
    }
    float* dst = convp + (size_t)lc * 16384 + b * 1024 + c * 16 + kk * 4;
    dst[0] = a0; dst[1] = a1; dst[2] = a2; dst[3] = a3;
}

// K2: convfin (blocks 0..63) + gamma reduce+log-softmax (64..79) + ctr resets
__global__ __launch_bounds__(256) void k2(const float* __restrict__ convp,
                                          const float* __restrict__ gpart,
                                          const float* __restrict__ bmu,
                                          const float* __restrict__ bsg,
                                          float* __restrict__ mus,
                                          float* __restrict__ isig,
                                          float* __restrict__ t1,
                                          float* __restrict__ loggam,
                                          unsigned* __restrict__ ctr) {
    int tid = threadIdx.x;
    if (blockIdx.x < 64) {
        int o = blockIdx.x * 256 + tid;     // 0..16383 = b*1024 + c*16 + kk
        float s = 0.0f;
        #pragma unroll 8
        for (int lc = 0; lc < LCH_; ++lc) s += convp[(size_t)lc * 16384 + o];
        int bc = o >> 4, kk = o & 15, k = kk & 7;
        if (kk < 8) {
            mus[bc * 8 + k] = s + bmu[k];
        } else {
            float logit = s + bsg[k];
            isig[bc * 8 + k] = expf(-logit);
            t1[bc * 8 + k] = -logit - 0.5f * LOG2PI_;
        }
    } else {
        int b = blockIdx.x - 64;
        if (b == 0 && tid < 17) ctr[tid] = 0u;   // reset ctrb[16] + ctr2
        if (tid < 64) {
            int lc = tid;
            bool valid = lc < LCH_;
            float g[K_];
            #pragma unroll
            for (int k = 0; k < K_; ++k)
                g[k] = valid ? gpart[(size_t)(lc * 16 + b) * 8 + k] : 0.0f;
            #pragma unroll
            for (int k = 0; k < K_; ++k)
                #pragma unroll
                for (int m = 1; m < 64; m <<= 1) g[k] += __shfl_xor(g[k], m);
            if (tid == 0) {
                float mx = -1e30f;
                #pragma unroll
                for (int k = 0; k < K_; ++k) mx = fmaxf(mx, g[k]);
                float sum = 0.0f;
                #pragma unroll
                for (int k = 0; k < K_; ++k) sum += expf(g[k] - mx);
                float lse = mx + logf(sum);
                #pragma unroll
                for (int k = 0; k < K_; ++k) loggam[b * 8 + k] = g[k] - lse;
            }
        }
    }
}

// K3: prod (all blocks) + per-b finisher (last block of b does whole-b LSE)
//     + global finisher (last of the 16 b-finishers reduces part -> out)
__global__ __launch_bounds__(256) void k3(const float* __restrict__ rep,
                                          const float* __restrict__ mus,
                                          const float* __restrict__ isig,
                                          const float* __restrict__ t1,
                                          const float* __restrict__ loggam,
                                          float* __restrict__ P,
                                          float* __restrict__ Spart,
                                          float* __restrict__ part,
                                          unsigned* __restrict__ ctr,
                                          float* __restrict__ out) {
    int b = blockIdx.x & 15, lc = blockIdx.x >> 4;
    int l0 = lc * 64;
    __shared__ float ldsA[64 * 65];
    __shared__ float sc[64];
    __shared__ float ldsMu[512], ldsIs[512], ldsT1[512];
    int tid = threadIdx.x, lane = tid & 63, wv = tid >> 6;
    const float4* r4 = (const float4*)rep;
    for (int i4 = tid; i4 < 1024; i4 += 256) {
        int ll = i4 >> 4, c4 = i4 & 15;
        int l = l0 + ll;
        float4 v = make_float4(0.f, 0.f, 0.f, 0.f);
        if (l < L_) {
            int n = l / T_, t = l - n * T_;
            v = r4[(size_t)((b * T_ + t) * N_ + n) * 16 + c4];
        }
        int base = ll * 65 + c4 * 4;
        ldsA[base] = v.x; ldsA[base+1] = v.y; ldsA[base+2] = v.z; ldsA[base+3] = v.w;
    }
    for (int idx = tid; idx < 512; idx += 256) {
        ldsMu[idx] = mus[b * 512 + idx];
        ldsIs[idx] = isig[b * 512 + idx];
        ldsT1[idx] = t1[b * 512 + idx];
    }
    __syncthreads();
    #pragma unroll 4
    for (int i = 0; i < 16; ++i) {
        int p = wv * 16 + i;
        float x = ldsA[p * 65 + lane];
        float ss = x * x;
        #pragma unroll
        for (int m = 1; m < 64; m <<= 1) ss += __shfl_xor(ss, m);
        if (lane == 0) sc[p] = 1.0f / fmaxf(sqrtf(ss), 1e-12f);
    }
    __syncthreads();
    int l = l0 + lane;
    bool valid = l < L_;
    int k0 = wv * 2, k1 = k0 + 1;
    float scv = sc[lane];
    float p0 = 1.0f, p1 = 1.0f;
    #pragma unroll 8
    for (int c = 0; c < 64; ++c) {
        float a = ldsA[lane * 65 + c] * scv;
        float z0 = (a - ldsMu[c * 8 + k0]) * ldsIs[c * 8 + k0];
        p0 *= ldsT1[c * 8 + k0] - 0.5f * z0 * z0;
        float z1 = (a - ldsMu[c * 8 + k1]) * ldsIs[c * 8 + k1];
        p1 *= ldsT1[c * 8 + k1] - 0.5f * z1 * z1;
    }
    if (!valid) { p0 = 0.0f; p1 = 0.0f; }
    if (valid) {
        P[(size_t)(b * K_ + k0) * L_ + l] = p0;
        P[(size_t)(b * K_ + k1) * L_ + l] = p1;
    }
    float v0 = p0 * p0, v1 = p1 * p1;
    #pragma unroll
    for (int m = 1; m < 64; m <<= 1) { v0 += __shfl_xor(v0, m); v1 += __shfl_xor(v1, m); }
    if (lane == 0) {
        Spart[(size_t)(b * K_ + k0) * LCH_ + lc] = v0;
        Spart[(size_t)(b * K_ + k1) * LCH_ + lc] = v1;
    }

    // ---- per-b completion: last of the 61 blocks of b does the LSE ----
    __threadfence();
    __shared__ bool lastB;
    if (tid == 0) {
        unsigned old = __hip_atomic_fetch_add(&ctr[b], 1u, __ATOMIC_ACQ_REL,
                                              __HIP_MEMORY_SCOPE_AGENT);
        lastB = (old == (unsigned)(LCH_ - 1));
    }
    __syncthreads();
    if (!lastB) return;
    __threadfence();

    __shared__ float invk[8], lgk[8];
    if (tid < 8) {
        float s = 0.0f;
        #pragma unroll 8
        for (int i = 0; i < LCH_; ++i) s += Spart[(size_t)(b * 8 + tid) * LCH_ + i];
        invk[tid] = 1.0f / fmaxf(sqrtf(s), 1e-12f);
        lgk[tid] = loggam[b * 8 + tid];
    }
    __syncthreads();
    float ll = 0.0f;
    for (int i = 0; i < 16; ++i) {
        int l2 = tid + 256 * i;
        if (l2 < L_) {
            float v[K_];
            float mx = -1e30f;
            #pragma unroll
            for (int k = 0; k < K_; ++k) {
                v[k] = P[(size_t)(b * K_ + k) * L_ + l2] * invk[k] + lgk[k];
                mx = fmaxf(mx, v[k]);
            }
            float s = 0.0f;
            #pragma unroll
            for (int k = 0; k < K_; ++k) s += expf(v[k] - mx);
            ll += mx + logf(s);
        }
    }
    #pragma unroll
    for (int m = 1; m < 64; m <<= 1) ll += __shfl_xor(ll, m);
    __shared__ float red[4];
    __shared__ bool last2;
    if (lane == 0) red[wv] = ll;
    __syncthreads();
    if (tid == 0) {
        part[b] = red[0] + red[1] + red[2] + red[3];
        __threadfence();
        unsigned old = __hip_atomic_fetch_add(&ctr[16], 1u, __ATOMIC_ACQ_REL,
                                              __HIP_MEMORY_SCOPE_AGENT);
        last2 = (old == 15u);
    }
    __syncthreads();
    if (last2 && tid == 0) {
        __threadfence();
        double s = 0.0;
        #pragma unroll
        for (int b2 = 0; b2 < B_; ++b2) s += (double)part[b2];
        out[0] = (float)(-s / ((double)B_ * (double)L_));
    }
}

extern "C" void kernel_launch(void* const* d_in, const int* in_sizes, int n_in,
                              void* d_out, int out_size, void* d_ws, size_t ws_size,
                              hipStream_t stream) {
    const float* rep     = (const float*)d_in[0];
    const float* rep_aug = (const float*)d_in[1];
    const float* Wg      = (const float*)d_in[2];
    const float* Wmu     = (const float*)d_in[3];
    const float* bmu     = (const float*)d_in[4];
    const float* Wsg     = (const float*)d_in[5];
    const float* bsg     = (const float*)d_in[6];
    float* out = (float*)d_out;
    float* ws  = (float*)d_ws;

    float* loggam  = ws + OFF_LOGGAM;
    float* part    = ws + OFF_PART;
    unsigned* ctr  = (unsigned*)(ws + OFF_CTR);
    float* mus     = ws + OFF_MUS;
    float* isig    = ws + OFF_ISIG;
    float* t1      = ws + OFF_T1;
    float* Spart   = ws + OFF_SPART;
    float* gpart   = ws + OFF_GPART;
    float* P       = ws + OFF_P;
    float* convp   = ws + OFF_CONVP;

    k1<<<B_ * LCH_, 256, 0, stream>>>(rep_aug, Wg, Wmu, Wsg, gpart, convp);
    k2<<<80, 256, 0, stream>>>(convp, gpart, bmu, bsg, mus, isig, t1, loggam, ctr);
    k3<<<B_ * LCH_, 256, 0, stream>>>(rep, mus, isig, t1, loggam, P, Spart, part, ctr, out);
}

// Round 8
// 61.267 us; speedup vs baseline: 2.5704x; 2.5704x over previous
//
#include <hip/hip_runtime.h>
#include <math.h>

#define B_ 16
#define T_ 12
#define N_ 325
#define C_ 64
#define K_ 8
#define L_ 3900            // N_*T_
#define M_ 249600          // C_*L_
#define LCH_ 61            // ceil(L_/64)
#define LOG2PI_ 1.8378770664093453f

// ---------------- workspace layout (floats) ----------------
#define OFF_LOGGAM 0            // 128
#define OFF_PART   128          // 256
#define OFF_CTR    384          // 1 unsigned
#define OFF_MUS    512          // 8192
#define OFF_ISIG   8704         // 8192
#define OFF_T1     16896        // 8192
#define OFF_SPART  25088        // 7808 = 128*61
#define OFF_GPART  32896        // 7808 = 976*8
#define OFF_P      40704        // 499200 = B*K*L
#define OFF_CONVP  539904       // 998400 = 61*16384
// total = 1538304 floats = 6.15 MB

// K1: per (lc,b): stage raw rep_aug tile, L2-normalize over C in-LDS,
//     conv partials (c=lane, LDS-only) + gamma partials (l=lane, coalesced Wg).
__global__ __launch_bounds__(256) void k1(const float* __restrict__ rep_aug,
                                          const float* __restrict__ Wg,
                                          const float* __restrict__ Wmu,
                                          const float* __restrict__ Wsg,
                                          float* __restrict__ gpart,
                                          float* __restrict__ convp) {
    int b = blockIdx.x & 15, lc = blockIdx.x >> 4;
    int l0 = lc * 64;
    __shared__ float ldsA[64 * 65];      // [ll][c]
    __shared__ float sc[64];
    __shared__ float ldsW[16 * 64];
    int tid = threadIdx.x, lane = tid & 63, wv = tid >> 6;
    const float4* r4 = (const float4*)rep_aug;
    for (int i4 = tid; i4 < 1024; i4 += 256) {
        int ll = i4 >> 4, c4 = i4 & 15;
        int l = l0 + ll;
        float4 v = make_float4(0.f, 0.f, 0.f, 0.f);
        if (l < L_) {
            int n = l / T_, t = l - n * T_;
            v = r4[(size_t)((b * T_ + t) * N_ + n) * 16 + c4];
        }
        int base = ll * 65 + c4 * 4;
        ldsA[base] = v.x; ldsA[base+1] = v.y; ldsA[base+2] = v.z; ldsA[base+3] = v.w;
    }
    for (int idx = tid; idx < 1024; idx += 256) {
        int r = idx >> 6, ll = idx & 63;
        int l = l0 + ll;
        float w = 0.0f;
        if (l < L_) w = (r < 8) ? Wmu[r * L_ + l] : Wsg[(r - 8) * L_ + l];
        ldsW[r * 64 + ll] = w;
    }
    __syncthreads();
    #pragma unroll 4
    for (int i = 0; i < 16; ++i) {
        int p = wv * 16 + i;
        float x = ldsA[p * 65 + lane];
        float ss = x * x;
        #pragma unroll
        for (int m = 1; m < 64; m <<= 1) ss += __shfl_xor(ss, m);
        if (lane == 0) sc[p] = 1.0f / fmaxf(sqrtf(ss), 1e-12f);
    }
    __syncthreads();

    // ---- gamma partials: lane = l (coalesced Wg), wave wv owns k0,k1 ----
    int k0 = wv * 2, k1i = k0 + 1;
    int lg = l0 + lane;
    int lcl = lg < L_ ? lg : 0;          // invalid lanes have a==0, load harmless
    const float* pg0 = Wg + (size_t)k0 * M_ + lcl;
    const float* pg1 = Wg + (size_t)k1i * M_ + lcl;
    float scv = sc[lane];
    float g0 = 0.f, g1 = 0.f;
    #pragma unroll 8
    for (int c = 0; c < 64; ++c) {
        float a = ldsA[lane * 65 + c] * scv;
        g0 = fmaf(a, pg0[(size_t)c * L_], g0);
        g1 = fmaf(a, pg1[(size_t)c * L_], g1);
    }
    #pragma unroll
    for (int m = 1; m < 64; m <<= 1) { g0 += __shfl_xor(g0, m); g1 += __shfl_xor(g1, m); }
    if (lane == 0) {
        gpart[(size_t)blockIdx.x * 8 + k0] = g0;
        gpart[(size_t)blockIdx.x * 8 + k1i] = g1;
    }

    // ---- conv partials: c = lane, kk = wv (LDS-only) ----
    int c = lane, kk = wv;
    const float* w0 = &ldsW[(kk * 4 + 0) * 64];
    const float* w1 = &ldsW[(kk * 4 + 1) * 64];
    const float* w2 = &ldsW[(kk * 4 + 2) * 64];
    const float* w3 = &ldsW[(kk * 4 + 3) * 64];
    float a0 = 0.f, a1 = 0.f, a2 = 0.f, a3 = 0.f;
    #pragma unroll 8
    for (int l = 0; l < 64; ++l) {
        float a = ldsA[l * 65 + c] * sc[l];
        a0 = fmaf(a, w0[l], a0);
        a1 = fmaf(a, w1[l], a1);
        a2 = fmaf(a, w2[l], a2);
        a3 = fmaf(a, w3[l], a3);
    }
    float* dst = convp + (size_t)lc * 16384 + b * 1024 + c * 16 + kk * 4;
    dst[0] = a0; dst[1] = a1; dst[2] = a2; dst[3] = a3;
}

// K2: convfin (blocks 0..63) + gamma reduce+log-softmax (64..79) + ctr reset
__global__ __launch_bounds__(256) void k2(const float* __restrict__ convp,
                                          const float* __restrict__ gpart,
                                          const float* __restrict__ bmu,
                                          const float* __restrict__ bsg,
                                          float* __restrict__ mus,
                                          float* __restrict__ isig,
                                          float* __restrict__ t1,
                                          float* __restrict__ loggam,
                                          unsigned* __restrict__ ctr) {
    int tid = threadIdx.x;
    if (blockIdx.x < 64) {
        int o = blockIdx.x * 256 + tid;     // 0..16383 = b*1024 + c*16 + kk
        float s = 0.0f;
        #pragma unroll 8
        for (int lc = 0; lc < LCH_; ++lc) s += convp[(size_t)lc * 16384 + o];
        int bc = o >> 4, kk = o & 15, k = kk & 7;
        if (kk < 8) {
            mus[bc * 8 + k] = s + bmu[k];
        } else {
            float logit = s + bsg[k];
            isig[bc * 8 + k] = expf(-logit);
            t1[bc * 8 + k] = -logit - 0.5f * LOG2PI_;
        }
    } else {
        int b = blockIdx.x - 64;
        if (b == 0 && tid == 0) *ctr = 0u;   // reset k4's completion counter
        if (tid < 64) {
            int lc = tid;
            bool valid = lc < LCH_;
            float g[K_];
            #pragma unroll
            for (int k = 0; k < K_; ++k)
                g[k] = valid ? gpart[(size_t)(lc * 16 + b) * 8 + k] : 0.0f;
            #pragma unroll
            for (int k = 0; k < K_; ++k)
                #pragma unroll
                for (int m = 1; m < 64; m <<= 1) g[k] += __shfl_xor(g[k], m);
            if (tid == 0) {
                float mx = -1e30f;
                #pragma unroll
                for (int k = 0; k < K_; ++k) mx = fmaxf(mx, g[k]);
                float sum = 0.0f;
                #pragma unroll
                for (int k = 0; k < K_; ++k) sum += expf(g[k] - mx);
                float lse = mx + logf(sum);
                #pragma unroll
                for (int k = 0; k < K_; ++k) loggam[b * 8 + k] = g[k] - lse;
            }
        }
    }
}

// K3: prod only. Block = (lc,b): P and Spart from raw rep (self-normalizing).
__global__ __launch_bounds__(256) void k3(const float* __restrict__ rep,
                                          const float* __restrict__ mus,
                                          const float* __restrict__ isig,
                                          const float* __restrict__ t1,
                                          float* __restrict__ P,
                                          float* __restrict__ Spart) {
    int b = blockIdx.x & 15, lc = blockIdx.x >> 4;
    int l0 = lc * 64;
    __shared__ float ldsA[64 * 65];
    __shared__ float sc[64];
    __shared__ float ldsMu[512], ldsIs[512], ldsT1[512];
    int tid = threadIdx.x, lane = tid & 63, wv = tid >> 6;
    const float4* r4 = (const float4*)rep;
    for (int i4 = tid; i4 < 1024; i4 += 256) {
        int ll = i4 >> 4, c4 = i4 & 15;
        int l = l0 + ll;
        float4 v = make_float4(0.f, 0.f, 0.f, 0.f);
        if (l < L_) {
            int n = l / T_, t = l - n * T_;
            v = r4[(size_t)((b * T_ + t) * N_ + n) * 16 + c4];
        }
        int base = ll * 65 + c4 * 4;
        ldsA[base] = v.x; ldsA[base+1] = v.y; ldsA[base+2] = v.z; ldsA[base+3] = v.w;
    }
    for (int idx = tid; idx < 512; idx += 256) {
        ldsMu[idx] = mus[b * 512 + idx];
        ldsIs[idx] = isig[b * 512 + idx];
        ldsT1[idx] = t1[b * 512 + idx];
    }
    __syncthreads();
    #pragma unroll 4
    for (int i = 0; i < 16; ++i) {
        int p = wv * 16 + i;
        float x = ldsA[p * 65 + lane];
        float ss = x * x;
        #pragma unroll
        for (int m = 1; m < 64; m <<= 1) ss += __shfl_xor(ss, m);
        if (lane == 0) sc[p] = 1.0f / fmaxf(sqrtf(ss), 1e-12f);
    }
    __syncthreads();
    int l = l0 + lane;
    bool valid = l < L_;
    int k0 = wv * 2, k1i = k0 + 1;
    float scv = sc[lane];
    float p0 = 1.0f, p1 = 1.0f;
    #pragma unroll 8
    for (int c = 0; c < 64; ++c) {
        float a = ldsA[lane * 65 + c] * scv;
        float z0 = (a - ldsMu[c * 8 + k0]) * ldsIs[c * 8 + k0];
        p0 *= ldsT1[c * 8 + k0] - 0.5f * z0 * z0;
        float z1 = (a - ldsMu[c * 8 + k1i]) * ldsIs[c * 8 + k1i];
        p1 *= ldsT1[c * 8 + k1i] - 0.5f * z1 * z1;
    }
    if (!valid) { p0 = 0.0f; p1 = 0.0f; }
    if (valid) {
        P[(size_t)(b * K_ + k0) * L_ + l] = p0;
        P[(size_t)(b * K_ + k1i) * L_ + l] = p1;
    }
    float v0 = p0 * p0, v1 = p1 * p1;
    #pragma unroll
    for (int m = 1; m < 64; m <<= 1) { v0 += __shfl_xor(v0, m); v1 += __shfl_xor(v1, m); }
    if (lane == 0) {
        Spart[(size_t)(b * K_ + k0) * LCH_ + lc] = v0;
        Spart[(size_t)(b * K_ + k1i) * LCH_ + lc] = v1;
    }
}

// K4: per-(b,256-l): invn from Spart, LSE over k, block partial;
//     last finished block reduces all 256 partials deterministically.
//     (release/acquire atomics only — NO __threadfence; R7 showed device
//      fences on the every-block path cost ~100µs on gfx950's split L2s.)
__global__ __launch_bounds__(256) void k4(const float* __restrict__ P,
                                          const float* __restrict__ Spart,
                                          const float* __restrict__ loggam,
                                          float* __restrict__ part,
                                          unsigned* __restrict__ ctr,
                                          float* __restrict__ out) {
    int b = blockIdx.x >> 4, ch = blockIdx.x & 15;
    int tid = threadIdx.x, lane = tid & 63, wv = tid >> 6;
    __shared__ float invk[8], lgk[8];
    if (tid < 8) {
        float s = 0.0f;
        #pragma unroll 8
        for (int i = 0; i < LCH_; ++i) s += Spart[(size_t)(b * 8 + tid) * LCH_ + i];
        invk[tid] = 1.0f / fmaxf(sqrtf(s), 1e-12f);
        lgk[tid] = loggam[b * 8 + tid];
    }
    __syncthreads();
    int l = ch * 256 + tid;
    float ll = 0.0f;
    if (l < L_) {
        float v[K_];
        float mx = -1e30f;
        #pragma unroll
        for (int k = 0; k < K_; ++k) {
            v[k] = P[(size_t)(b * K_ + k) * L_ + l] * invk[k] + lgk[k];
            mx = fmaxf(mx, v[k]);
        }
        float s = 0.0f;
        #pragma unroll
        for (int k = 0; k < K_; ++k) s += expf(v[k] - mx);
        ll = mx + logf(s);
    }
    #pragma unroll
    for (int m = 1; m < 64; m <<= 1) ll += __shfl_xor(ll, m);
    __shared__ float red[4];
    __shared__ bool last;
    if (lane == 0) red[wv] = ll;
    __syncthreads();
    if (tid == 0) {
        float v = red[0] + red[1] + red[2] + red[3];
        __hip_atomic_store(&part[blockIdx.x], v, __ATOMIC_RELEASE, __HIP_MEMORY_SCOPE_AGENT);
        unsigned old = __hip_atomic_fetch_add(ctr, 1u, __ATOMIC_ACQ_REL, __HIP_MEMORY_SCOPE_AGENT);
        last = (old == 255u);
    }
    __syncthreads();
    if (last) {
        float v = __hip_atomic_load(&part[tid], __ATOMIC_ACQUIRE, __HIP_MEMORY_SCOPE_AGENT);
        double d = (double)v;
        #pragma unroll
        for (int m = 1; m < 64; m <<= 1) d += __shfl_xor(d, m);
        __shared__ double dred[4];
        if (lane == 0) dred[wv] = d;
        __syncthreads();
        if (tid == 0)
            out[0] = (float)(-(dred[0] + dred[1] + dred[2] + dred[3]) /
                             ((double)B_ * (double)L_));
    }
}

extern "C" void kernel_launch(void* const* d_in, const int* in_sizes, int n_in,
                              void* d_out, int out_size, void* d_ws, size_t ws_size,
                              hipStream_t stream) {
    const float* rep     = (const float*)d_in[0];
    const float* rep_aug = (const float*)d_in[1];
    const float* Wg      = (const float*)d_in[2];
    const float* Wmu     = (const float*)d_in[3];
    const float* bmu     = (const float*)d_in[4];
    const float* Wsg     = (const float*)d_in[5];
    const float* bsg     = (const float*)d_in[6];
    float* out = (float*)d_out;
    float* ws  = (float*)d_ws;

    float* loggam  = ws + OFF_LOGGAM;
    float* part    = ws + OFF_PART;
    unsigned* ctr  = (unsigned*)(ws + OFF_CTR);
    float* mus     = ws + OFF_MUS;
    float* isig    = ws + OFF_ISIG;
    float* t1      = ws + OFF_T1;
    float* Spart   = ws + OFF_SPART;
    float* gpart   = ws + OFF_GPART;
    float* P       = ws + OFF_P;
    float* convp   = ws + OFF_CONVP;

    k1<<<B_ * LCH_, 256, 0, stream>>>(rep_aug, Wg, Wmu, Wsg, gpart, convp);
    k2<<<80, 256, 0, stream>>>(convp, gpart, bmu, bsg, mus, isig, t1, loggam, ctr);
    k3<<<B_ * LCH_, 256, 0, stream>>>(rep, mus, isig, t1, P, Spart);
    k4<<<B_ * 16, 256, 0, stream>>>(P, Spart, loggam, part, ctr, out);
}